// Round 9
// baseline (153.380 us; speedup 1.0000x reference)
//
#include <hip/hip_runtime.h>
#include <cstddef>

#define CTXDIM 256
#define RANK 8
#define KW 7
#define SCALE 0.17677669529663687f
#define NPIX 16384
#define PLANE (NPIX * 128)     // floats per fp32 qkv plane
#define HPC 14                 // halo cols
#define HPR 10                 // halo rows (4-row half-tile + 2*3)
#define NHALO 140              // 10*14
#define LSTRIDE 36
#define WSTRIDE 136            // fp16 LDS tile stride

typedef _Float16 half8 __attribute__((ext_vector_type(8)));
typedef _Float16 half4 __attribute__((ext_vector_type(4)));
typedef float floatx4 __attribute__((ext_vector_type(4)));

struct Params {
  const float *x, *ctx, *Wqkv, *bqkv, *A, *Blora, *Vlora;
  const float *g1w, *g1b, *g2w, *g2b, *Wproj, *bproj;
  float* out;
  float* qkv;       // planar fp32 [3][N][128]
};

// ---- cal[b][r] = alpha_b * (ctx[b] @ Blora)[r]; wave b handles batch b ----
__device__ __forceinline__ void compute_cal(const Params& p, int tid,
                                            float* cal_s) {
  const int b = tid >> 6, lane = tid & 63;
  const float c0 = p.ctx[b * CTXDIM + lane];
  const float c1 = p.ctx[b * CTXDIM + 64 + lane];
  const float c2 = p.ctx[b * CTXDIM + 128 + lane];
  const float c3 = p.ctx[b * CTXDIM + 192 + lane];
  float cp[RANK];
#pragma unroll
  for (int r = 0; r < RANK; ++r) {
    float q = c0 * p.Blora[lane * RANK + r] + c1 * p.Blora[(64 + lane) * RANK + r] +
              c2 * p.Blora[(128 + lane) * RANK + r] + c3 * p.Blora[(192 + lane) * RANK + r];
#pragma unroll
    for (int s = 32; s; s >>= 1) q += __shfl_xor(q, s, 64);
    cp[r] = q;
  }
  float gacc = 0.f;
#pragma unroll
  for (int h = 0; h < 16; ++h) {
    float q = c0 * p.g1w[h * CTXDIM + lane] + c1 * p.g1w[h * CTXDIM + 64 + lane] +
              c2 * p.g1w[h * CTXDIM + 128 + lane] + c3 * p.g1w[h * CTXDIM + 192 + lane];
#pragma unroll
    for (int s = 32; s; s >>= 1) q += __shfl_xor(q, s, 64);
    gacc += fmaxf(q + p.g1b[h], 0.f) * p.g2w[h];
  }
  if (lane == 0) {
    const float alpha = 1.f / (1.f + __expf(-(gacc + p.g2b[0])));
#pragma unroll
    for (int r = 0; r < RANK; ++r) cal_s[b * RANK + r] = alpha * cp[r];
  }
}

// ---- stage 64 fp32 rows (row stride 128) -> LDS fp16 [64][WSTRIDE] ----
__device__ __forceinline__ void stage_rows_f16(const float* __restrict__ src,
                                               _Float16* dst, int tid) {
  const int row = tid >> 2;
  const int c0 = (tid & 3) * 32;
  const float* sp = src + (size_t)row * 128 + c0;
  _Float16* dp = dst + row * WSTRIDE + c0;
#pragma unroll
  for (int i = 0; i < 4; ++i) {
    const float4 a = *(const float4*)(sp + i * 8);
    const float4 b = *(const float4*)(sp + i * 8 + 4);
    half8 o;
    o[0] = (_Float16)a.x; o[1] = (_Float16)a.y;
    o[2] = (_Float16)a.z; o[3] = (_Float16)a.w;
    o[4] = (_Float16)b.x; o[5] = (_Float16)b.y;
    o[6] = (_Float16)b.z; o[7] = (_Float16)b.w;
    *(half8*)(dp + i * 8) = o;
  }
}

// ---------------------------------------------------------------------------
// K1: QKV GEMM with block-local prep (unchanged from R8 — qkv bit-identical).
// ---------------------------------------------------------------------------
__global__ __launch_bounds__(256) void gemm1_kernel(Params p) {
  __shared__ __align__(16) _Float16 xs[64 * WSTRIDE];
  __shared__ __align__(16) _Float16 wsh[64 * WSTRIDE];
  __shared__ float cal_s[32];
  const int tid = threadIdx.x;
  const int bx = blockIdx.x, by = blockIdx.y, z = blockIdx.z;
  const int m0 = z * 4096 + bx * 64;
  const int n0 = by * 64;

  compute_cal(p, tid, cal_s);
  stage_rows_f16(p.x + (size_t)m0 * 128, xs, tid);
  __syncthreads();

  {
    const int k = tid & 127;
    const int half = tid >> 7;
    const float4 a0 = *(const float4*)&p.A[k * RANK];
    const float4 a1 = *(const float4*)&p.A[k * RANK + 4];
    const float* cb = &cal_s[z * RANK];
    const float c0 = cb[0], c1 = cb[1], c2 = cb[2], c3 = cb[3];
    const float c4 = cb[4], c5 = cb[5], c6 = cb[6], c7 = cb[7];
#pragma unroll
    for (int rr = 0; rr < 32; ++rr) {
      const int row = half * 32 + rr;
      const int o = n0 + row;
      const float4 v0 = *(const float4*)&p.Vlora[o * RANK];
      const float4 v1 = *(const float4*)&p.Vlora[o * RANK + 4];
      float d = a0.x * v0.x * c0;
      d = fmaf(a0.y * v0.y, c1, d);
      d = fmaf(a0.z * v0.z, c2, d);
      d = fmaf(a0.w * v0.w, c3, d);
      d = fmaf(a1.x * v1.x, c4, d);
      d = fmaf(a1.y * v1.y, c5, d);
      d = fmaf(a1.z * v1.z, c6, d);
      d = fmaf(a1.w * v1.w, c7, d);
      wsh[row * WSTRIDE + k] = (_Float16)(p.Wqkv[o * 128 + k] + d);
    }
  }
  __syncthreads();

  const int lane = tid & 63;
  const int w = tid >> 6;
  const int r = lane & 15;
  const int quad = lane >> 4;
  const _Float16* ap = xs + (w * 16 + r) * WSTRIDE + quad * 8;
  const _Float16* bp = wsh + r * WSTRIDE + quad * 8;

  floatx4 acc0 = {0.f, 0.f, 0.f, 0.f};
  floatx4 acc1 = acc0, acc2 = acc0, acc3 = acc0;
#pragma unroll
  for (int kc = 0; kc < 4; ++kc) {
    const half8 a  = *(const half8*)(ap + kc * 32);
    const half8 b0 = *(const half8*)(bp + kc * 32);
    const half8 b1 = *(const half8*)(bp + 16 * WSTRIDE + kc * 32);
    const half8 b2 = *(const half8*)(bp + 32 * WSTRIDE + kc * 32);
    const half8 b3 = *(const half8*)(bp + 48 * WSTRIDE + kc * 32);
    acc0 = __builtin_amdgcn_mfma_f32_16x16x32_f16(a, b0, acc0, 0, 0, 0);
    acc1 = __builtin_amdgcn_mfma_f32_16x16x32_f16(a, b1, acc1, 0, 0, 0);
    acc2 = __builtin_amdgcn_mfma_f32_16x16x32_f16(a, b2, acc2, 0, 0, 0);
    acc3 = __builtin_amdgcn_mfma_f32_16x16x32_f16(a, b3, acc3, 0, 0, 0);
  }

  const int mbase = m0 + w * 16 + quad * 4;
  floatx4 accs[4] = {acc0, acc1, acc2, acc3};
#pragma unroll
  for (int nt = 0; nt < 4; ++nt) {
    const int ncol = n0 + nt * 16 + r;
    const float bv = p.bqkv[ncol];
    float* cp = p.qkv + (size_t)(ncol >> 7) * PLANE + (size_t)mbase * 128 + (ncol & 127);
#pragma unroll
    for (int reg = 0; reg < 4; ++reg)
      cp[(size_t)reg * 128] = accs[nt][reg] + bv;
  }
}

// ---------------------------------------------------------------------------
// K2: fused neighborhood attention + projection GEMM.
// Block = (b, ti, tj, s): 4x8 pixel half-tile (rows ti*8+s*4..+3, cols tj*8..+7).
// Per head h (sequential): stage 10x14 fp32 K-halo -> logits -> softmax ->
// stage V (same buffer) -> PV -> write fp16 A-tile slice to at_s.
// Then: stage full Wproj (128x128) -> LDS fp16, MFMA at_s @ Wproj^T + bias,
// store final out.  Zero-fill OOB halo = reference zero-pad softmax semantics.
// 8 threads/pixel (4 dims each), 3-shuffle logit reduce.
// LDS: union(kv fp32 20.2 KB, Wproj fp16 34.8 KB) + at_s 8.7 KB = 43.5 KB.
// ---------------------------------------------------------------------------
__global__ __launch_bounds__(256) void attnproj_kernel(Params p) {
  __shared__ __align__(16) unsigned char smem_u[128 * WSTRIDE * 2]; // 34816 B
  __shared__ __align__(16) _Float16 at_s[32 * WSTRIDE];             // 8704 B
  float* kvf = (float*)smem_u;
  _Float16* bs = (_Float16*)smem_u;

  const int bid = blockIdx.x;            // [0,512)
  const int s  = bid & 1;
  const int tj = (bid >> 1) & 7;
  const int ti = (bid >> 4) & 7;
  const int b  = bid >> 7;
  const int t  = threadIdx.x;

  const float* kpl = p.qkv + PLANE;
  const float* vpl = p.qkv + 2 * (size_t)PLANE;

  // ---- staging offsets (halo 10x14, 1120 float4 slots, 5 iters) ----
  const int i0 = ti * 8 + s * 4 - 3;
  const int j0 = tj * 8 - 3;
  int lofs[5], gof0[5];
#pragma unroll
  for (int r = 0; r < 5; ++r) {
    const int f4 = t + r * 256;
    lofs[r] = -1; gof0[r] = -1;
    if (f4 < NHALO * 8) {
      const int pp = f4 >> 3;            // halo pixel 0..139
      const int d = (f4 & 7) * 4;        // dim offset within head
      const int hr = pp / HPC;
      const int hc = pp - hr * HPC;
      const int ii = i0 + hr;
      const int jj = j0 + hc;
      lofs[r] = pp * LSTRIDE + d;
      if ((unsigned)ii < 64u && (unsigned)jj < 64u)
        gof0[r] = (b * 4096 + ii * 64 + jj) * 128 + d;
    }
  }

  // ---- per-thread pixel mapping: 8 thr/pixel, 4 dims each ----
  const int pix = t >> 3;                // 0..31 local pixel
  const int oct = t & 7;                 // dim octant
  const int pi = pix >> 3;               // 0..3 local row
  const int pj = pix & 7;                // 0..7 local col
  const int n = b * 4096 + (ti * 8 + s * 4 + pi) * 64 + tj * 8 + pj;
  const int dbase = oct * 4;

#pragma unroll
  for (int h = 0; h < 4; ++h) {
    // q slice for this head
    const float4 qv = *(const float4*)(p.qkv + (size_t)n * 128 + h * 32 + dbase);

    __syncthreads();                     // protect kvf from previous pass
    // stage K(h)
#pragma unroll
    for (int r = 0; r < 5; ++r) {
      if (lofs[r] >= 0) {
        float4 kv = make_float4(0.f, 0.f, 0.f, 0.f);
        if (gof0[r] >= 0) kv = *(const float4*)(kpl + gof0[r] + h * 32);
        *(float4*)&kvf[lofs[r]] = kv;
      }
    }
    __syncthreads();

    float l[49];
#pragma unroll
    for (int di = 0; di < KW; ++di) {
#pragma unroll
      for (int dj = 0; dj < KW; ++dj) {
        const int hp = (pi + di) * HPC + (pj + dj);
        const float4 kv = *(const float4*)&kvf[hp * LSTRIDE + dbase];
        float pr = qv.x * kv.x + qv.y * kv.y + qv.z * kv.z + qv.w * kv.w;
        pr += __shfl_xor(pr, 1, 64);
        pr += __shfl_xor(pr, 2, 64);
        pr += __shfl_xor(pr, 4, 64);
        l[di * KW + dj] = pr * SCALE;
      }
    }

    float mx = l[0];
#pragma unroll
    for (int k = 1; k < 49; ++k) mx = fmaxf(mx, l[k]);
    float sum = 0.f;
#pragma unroll
    for (int k = 0; k < 49; ++k) {
      const float w = __expf(l[k] - mx);
      l[k] = w;
      sum += w;
    }
    const float inv = 1.f / sum;

    __syncthreads();                     // done reading K
    // stage V(h)
#pragma unroll
    for (int r = 0; r < 5; ++r) {
      if (lofs[r] >= 0) {
        float4 vv = make_float4(0.f, 0.f, 0.f, 0.f);
        if (gof0[r] >= 0) vv = *(const float4*)(vpl + gof0[r] + h * 32);
        *(float4*)&kvf[lofs[r]] = vv;
      }
    }
    __syncthreads();

    float o0 = 0.f, o1 = 0.f, o2 = 0.f, o3 = 0.f;
#pragma unroll
    for (int di = 0; di < KW; ++di) {
#pragma unroll
      for (int dj = 0; dj < KW; ++dj) {
        const int hp = (pi + di) * HPC + (pj + dj);
        const float w = l[di * KW + dj];
        const float4 vv = *(const float4*)&kvf[hp * LSTRIDE + dbase];
        o0 = fmaf(w, vv.x, o0); o1 = fmaf(w, vv.y, o1);
        o2 = fmaf(w, vv.z, o2); o3 = fmaf(w, vv.w, o3);
      }
    }

    half4 ov;
    ov[0] = (_Float16)(o0 * inv); ov[1] = (_Float16)(o1 * inv);
    ov[2] = (_Float16)(o2 * inv); ov[3] = (_Float16)(o3 * inv);
    *(half4*)&at_s[pix * WSTRIDE + h * 32 + dbase] = ov;
  }

  __syncthreads();                       // at_s complete; kvf free

  // ---- stage Wproj 128x128 fp32 -> bs fp16 (stride WSTRIDE) ----
  {
    const int row = t >> 1;              // 0..127
    const int c0 = (t & 1) * 64;
    const float* sp = p.Wproj + (size_t)row * 128 + c0;
    _Float16* dp = bs + row * WSTRIDE + c0;
#pragma unroll
    for (int i = 0; i < 8; ++i) {
      const float4 a = *(const float4*)(sp + i * 8);
      const float4 b4 = *(const float4*)(sp + i * 8 + 4);
      half8 o;
      o[0] = (_Float16)a.x; o[1] = (_Float16)a.y;
      o[2] = (_Float16)a.z; o[3] = (_Float16)a.w;
      o[4] = (_Float16)b4.x; o[5] = (_Float16)b4.y;
      o[6] = (_Float16)b4.z; o[7] = (_Float16)b4.w;
      *(half8*)(dp + i * 8) = o;
    }
  }
  __syncthreads();

  // ---- projection MFMA: wave w -> rows (w&1)*16..+15, cols (w>>1)*64..+63 ----
  const int lane = t & 63;
  const int w = t >> 6;
  const int r = lane & 15;
  const int quad = lane >> 4;
  const int nh = w >> 1;
  const _Float16* ap = at_s + ((w & 1) * 16 + r) * WSTRIDE + quad * 8;
  const _Float16* bp = bs + (nh * 64 + r) * WSTRIDE + quad * 8;

  floatx4 acc0 = {0.f, 0.f, 0.f, 0.f};
  floatx4 acc1 = acc0, acc2 = acc0, acc3 = acc0;
#pragma unroll
  for (int kc = 0; kc < 4; ++kc) {
    const half8 a  = *(const half8*)(ap + kc * 32);
    const half8 b0 = *(const half8*)(bp + kc * 32);
    const half8 b1 = *(const half8*)(bp + 16 * WSTRIDE + kc * 32);
    const half8 b2 = *(const half8*)(bp + 32 * WSTRIDE + kc * 32);
    const half8 b3 = *(const half8*)(bp + 48 * WSTRIDE + kc * 32);
    acc0 = __builtin_amdgcn_mfma_f32_16x16x32_f16(a, b0, acc0, 0, 0, 0);
    acc1 = __builtin_amdgcn_mfma_f32_16x16x32_f16(a, b1, acc1, 0, 0, 0);
    acc2 = __builtin_amdgcn_mfma_f32_16x16x32_f16(a, b2, acc2, 0, 0, 0);
    acc3 = __builtin_amdgcn_mfma_f32_16x16x32_f16(a, b3, acc3, 0, 0, 0);
  }

  // local pixel P0 = (w&1)*16 + quad*4 (+reg stays in same spatial row)
  const int P0 = (w & 1) * 16 + quad * 4;
  const int growbase = b * 4096 + (ti * 8 + s * 4 + (P0 >> 3)) * 64 + tj * 8 + (P0 & 7);
  floatx4 accs[4] = {acc0, acc1, acc2, acc3};
#pragma unroll
  for (int nt = 0; nt < 4; ++nt) {
    const int ncol = nh * 64 + nt * 16 + r;
    const float bv = p.bproj[ncol];
    float* cp = p.out + (size_t)growbase * 128 + ncol;
#pragma unroll
    for (int reg = 0; reg < 4; ++reg)
      cp[(size_t)reg * 128] = accs[nt][reg] + bv;
  }
}

// ---------------------------------------------------------------------------
// Workspace: [5 MB, 29 MB) qkv [3][16384][128] fp32 planar.
// ---------------------------------------------------------------------------
extern "C" void kernel_launch(void* const* d_in, const int* in_sizes, int n_in,
                              void* d_out, int out_size, void* d_ws, size_t ws_size,
                              hipStream_t stream) {
  char* ws = (char*)d_ws;
  Params hp;
  hp.x     = (const float*)d_in[0];
  hp.ctx   = (const float*)d_in[1];
  hp.Wqkv  = (const float*)d_in[2];
  hp.bqkv  = (const float*)d_in[3];
  hp.A     = (const float*)d_in[4];
  hp.Blora = (const float*)d_in[5];
  hp.Vlora = (const float*)d_in[6];
  hp.g1w   = (const float*)d_in[7];
  hp.g1b   = (const float*)d_in[8];
  hp.g2w   = (const float*)d_in[9];
  hp.g2b   = (const float*)d_in[10];
  hp.Wproj = (const float*)d_in[11];
  hp.bproj = (const float*)d_in[12];
  hp.out   = (float*)d_out;
  hp.qkv   = (float*)(ws + (5u << 20));

  gemm1_kernel<<<dim3(64, 6, 4), 256, 0, stream>>>(hp);
  attnproj_kernel<<<512, 256, 0, stream>>>(hp);
}

// Round 10
// 132.215 us; speedup vs baseline: 1.1601x; 1.1601x over previous
//
#include <hip/hip_runtime.h>
#include <cstddef>

#define CTXDIM 256
#define RANK 8
#define KW 7
#define SCALE 0.17677669529663687f
#define NPIX 16384
#define PLANE16 (NPIX * 128)   // elems per fp16 qkv plane
#define HR 14                  // halo rows (8 + 6)
#define HC 22                  // halo cols (16 + 6)
#define NH 308                 // HR*HC
#define KST 40                 // fp16 LDS stride per halo pixel (80 B, 16B-aligned)
#define WSTRIDE 136            // fp16 LDS tile stride for GEMM staging

typedef _Float16 half8 __attribute__((ext_vector_type(8)));
typedef _Float16 half2_t __attribute__((ext_vector_type(2)));
typedef float floatx4 __attribute__((ext_vector_type(4)));

#if defined(__has_builtin)
#if __has_builtin(__builtin_amdgcn_fdot2)
#define HAVE_FDOT2 1
#endif
#endif

struct Params {
  const float *x, *ctx, *Wqkv, *bqkv, *A, *Blora, *Vlora;
  const float *g1w, *g1b, *g2w, *g2b, *Wproj, *bproj;
  float* out;
  _Float16* qkv16;   // planar fp16 [3][N][128]
  _Float16* at16;    // attention output fp16 [N][128]
};

// ---- cal[b][r] = alpha_b * (ctx[b] @ Blora)[r]; wave b handles batch b ----
__device__ __forceinline__ void compute_cal(const Params& p, int tid,
                                            float* cal_s) {
  const int b = tid >> 6, lane = tid & 63;
  const float c0 = p.ctx[b * CTXDIM + lane];
  const float c1 = p.ctx[b * CTXDIM + 64 + lane];
  const float c2 = p.ctx[b * CTXDIM + 128 + lane];
  const float c3 = p.ctx[b * CTXDIM + 192 + lane];
  float cp[RANK];
#pragma unroll
  for (int r = 0; r < RANK; ++r) {
    float q = c0 * p.Blora[lane * RANK + r] + c1 * p.Blora[(64 + lane) * RANK + r] +
              c2 * p.Blora[(128 + lane) * RANK + r] + c3 * p.Blora[(192 + lane) * RANK + r];
#pragma unroll
    for (int s = 32; s; s >>= 1) q += __shfl_xor(q, s, 64);
    cp[r] = q;
  }
  float gacc = 0.f;
#pragma unroll
  for (int h = 0; h < 16; ++h) {
    float q = c0 * p.g1w[h * CTXDIM + lane] + c1 * p.g1w[h * CTXDIM + 64 + lane] +
              c2 * p.g1w[h * CTXDIM + 128 + lane] + c3 * p.g1w[h * CTXDIM + 192 + lane];
#pragma unroll
    for (int s = 32; s; s >>= 1) q += __shfl_xor(q, s, 64);
    gacc += fmaxf(q + p.g1b[h], 0.f) * p.g2w[h];
  }
  if (lane == 0) {
    const float alpha = 1.f / (1.f + __expf(-(gacc + p.g2b[0])));
#pragma unroll
    for (int r = 0; r < RANK; ++r) cal_s[b * RANK + r] = alpha * cp[r];
  }
}

// ---- stage 64 fp32 rows (row stride 128) -> LDS fp16 [64][WSTRIDE] ----
__device__ __forceinline__ void stage_rows_f16(const float* __restrict__ src,
                                               _Float16* dst, int tid) {
  const int row = tid >> 2;
  const int c0 = (tid & 3) * 32;
  const float* sp = src + (size_t)row * 128 + c0;
  _Float16* dp = dst + row * WSTRIDE + c0;
#pragma unroll
  for (int i = 0; i < 4; ++i) {
    const float4 a = *(const float4*)(sp + i * 8);
    const float4 b = *(const float4*)(sp + i * 8 + 4);
    half8 o;
    o[0] = (_Float16)a.x; o[1] = (_Float16)a.y;
    o[2] = (_Float16)a.z; o[3] = (_Float16)a.w;
    o[4] = (_Float16)b.x; o[5] = (_Float16)b.y;
    o[6] = (_Float16)b.z; o[7] = (_Float16)b.w;
    *(half8*)(dp + i * 8) = o;
  }
}

// ---------------------------------------------------------------------------
// K1: QKV GEMM with block-local prep (R8 structure; output planes now fp16).
// ---------------------------------------------------------------------------
__global__ __launch_bounds__(256) void gemm1_kernel(Params p) {
  __shared__ __align__(16) _Float16 xs[64 * WSTRIDE];
  __shared__ __align__(16) _Float16 wsh[64 * WSTRIDE];
  __shared__ float cal_s[32];
  const int tid = threadIdx.x;
  const int bx = blockIdx.x, by = blockIdx.y, z = blockIdx.z;
  const int m0 = z * 4096 + bx * 64;
  const int n0 = by * 64;

  compute_cal(p, tid, cal_s);
  stage_rows_f16(p.x + (size_t)m0 * 128, xs, tid);
  __syncthreads();

  {
    const int k = tid & 127;
    const int half = tid >> 7;
    const float4 a0 = *(const float4*)&p.A[k * RANK];
    const float4 a1 = *(const float4*)&p.A[k * RANK + 4];
    const float* cb = &cal_s[z * RANK];
    const float c0 = cb[0], c1 = cb[1], c2 = cb[2], c3 = cb[3];
    const float c4 = cb[4], c5 = cb[5], c6 = cb[6], c7 = cb[7];
#pragma unroll
    for (int rr = 0; rr < 32; ++rr) {
      const int row = half * 32 + rr;
      const int o = n0 + row;
      const float4 v0 = *(const float4*)&p.Vlora[o * RANK];
      const float4 v1 = *(const float4*)&p.Vlora[o * RANK + 4];
      float d = a0.x * v0.x * c0;
      d = fmaf(a0.y * v0.y, c1, d);
      d = fmaf(a0.z * v0.z, c2, d);
      d = fmaf(a0.w * v0.w, c3, d);
      d = fmaf(a1.x * v1.x, c4, d);
      d = fmaf(a1.y * v1.y, c5, d);
      d = fmaf(a1.z * v1.z, c6, d);
      d = fmaf(a1.w * v1.w, c7, d);
      wsh[row * WSTRIDE + k] = (_Float16)(p.Wqkv[o * 128 + k] + d);
    }
  }
  __syncthreads();

  const int lane = tid & 63;
  const int w = tid >> 6;
  const int r = lane & 15;
  const int quad = lane >> 4;
  const _Float16* ap = xs + (w * 16 + r) * WSTRIDE + quad * 8;
  const _Float16* bp = wsh + r * WSTRIDE + quad * 8;

  floatx4 acc0 = {0.f, 0.f, 0.f, 0.f};
  floatx4 acc1 = acc0, acc2 = acc0, acc3 = acc0;
#pragma unroll
  for (int kc = 0; kc < 4; ++kc) {
    const half8 a  = *(const half8*)(ap + kc * 32);
    const half8 b0 = *(const half8*)(bp + kc * 32);
    const half8 b1 = *(const half8*)(bp + 16 * WSTRIDE + kc * 32);
    const half8 b2 = *(const half8*)(bp + 32 * WSTRIDE + kc * 32);
    const half8 b3 = *(const half8*)(bp + 48 * WSTRIDE + kc * 32);
    acc0 = __builtin_amdgcn_mfma_f32_16x16x32_f16(a, b0, acc0, 0, 0, 0);
    acc1 = __builtin_amdgcn_mfma_f32_16x16x32_f16(a, b1, acc1, 0, 0, 0);
    acc2 = __builtin_amdgcn_mfma_f32_16x16x32_f16(a, b2, acc2, 0, 0, 0);
    acc3 = __builtin_amdgcn_mfma_f32_16x16x32_f16(a, b3, acc3, 0, 0, 0);
  }

  const int mbase = m0 + w * 16 + quad * 4;
  floatx4 accs[4] = {acc0, acc1, acc2, acc3};
#pragma unroll
  for (int nt = 0; nt < 4; ++nt) {
    const int ncol = n0 + nt * 16 + r;
    const float bv = p.bqkv[ncol];
    _Float16* cp = p.qkv16 + (size_t)(ncol >> 7) * PLANE16 +
                   (size_t)mbase * 128 + (ncol & 127);
#pragma unroll
    for (int reg = 0; reg < 4; ++reg)
      cp[(size_t)reg * 128] = (_Float16)(accs[nt][reg] + bv);
  }
}

// ---------------------------------------------------------------------------
// K2: neighborhood attention, fp16 K/V LDS path.
// Block = (b, ti 0..7, tj 0..3, h): 8x16 pixel tile, one head; 512 blocks.
// 2 threads/pixel (16 dims each).  14x22 fp16 K AND V halos staged at once
// (49 KB LDS, one barrier).  Zero-fill OOB = reference zero-pad softmax.
// Logits: v_dot2_f32_f16 (fallback scalar) + one xor-shuffle (DPP).
// PV: fp16 reads, fp32 accumulate.  Output fp16 [N][128].
// ---------------------------------------------------------------------------
__global__ __launch_bounds__(256) void attn_kernel(Params p) {
  __shared__ __align__(16) _Float16 ks16[NH * KST];
  __shared__ __align__(16) _Float16 vs16[NH * KST];

  const int bid = blockIdx.x;        // [0,512)
  const int h  = bid & 3;
  const int tj = (bid >> 2) & 3;
  const int ti = (bid >> 4) & 7;
  const int b  = bid >> 7;
  const int tid = threadIdx.x;

  const _Float16* kpl = p.qkv16 + PLANE16;
  const _Float16* vpl = p.qkv16 + 2 * (size_t)PLANE16;

  const int i0 = ti * 8 - 3;
  const int j0 = tj * 16 - 3;

  // ---- stage K and V halos (308 pixels x 32 fp16 dims each) ----
#pragma unroll
  for (int it = 0; it < 5; ++it) {
    const int s = tid + it * 256;       // half8 slot, [0,1232)
    if (s < NH * 4) {
      const int pp = s >> 2;
      const int d8 = (s & 3) * 8;
      const int hr = pp / HC;
      const int hc = pp - hr * HC;
      const int ii = i0 + hr;
      const int jj = j0 + hc;
      half8 kv = {0, 0, 0, 0, 0, 0, 0, 0};
      half8 vv = {0, 0, 0, 0, 0, 0, 0, 0};
      if ((unsigned)ii < 64u && (unsigned)jj < 64u) {
        const size_t g = (size_t)(b * 4096 + ii * 64 + jj) * 128 + h * 32 + d8;
        kv = *(const half8*)(kpl + g);
        vv = *(const half8*)(vpl + g);
      }
      *(half8*)&ks16[pp * KST + d8] = kv;
      *(half8*)&vs16[pp * KST + d8] = vv;
    }
  }
  __syncthreads();

  // ---- per-thread mapping: pixel = tid>>1, 16-dim half = tid&1 ----
  const int pix = tid >> 1;            // 0..127
  const int hf = tid & 1;
  const int pi = pix >> 4;             // 0..7
  const int pj = pix & 15;             // 0..15
  const int n = b * 4096 + (ti * 8 + pi) * 64 + tj * 16 + pj;
  const int dbase = hf * 16;

  // q: 16 fp16 dims kept in fp16 regs
  const half8 q0 = *(const half8*)(p.qkv16 + (size_t)n * 128 + h * 32 + dbase);
  const half8 q1 = *(const half8*)(p.qkv16 + (size_t)n * 128 + h * 32 + dbase + 8);

  float l[49];
#pragma unroll
  for (int di = 0; di < KW; ++di) {
#pragma unroll
    for (int dj = 0; dj < KW; ++dj) {
      const int hp = (pi + di) * HC + (pj + dj);
      const _Float16* kp = &ks16[hp * KST + dbase];
      const half8 k0 = *(const half8*)kp;
      const half8 k1 = *(const half8*)(kp + 8);
      float pr = 0.f;
#ifdef HAVE_FDOT2
#pragma unroll
      for (int e = 0; e < 4; ++e) {
        half2_t qa = {q0[2 * e], q0[2 * e + 1]};
        half2_t ka = {k0[2 * e], k0[2 * e + 1]};
        pr = __builtin_amdgcn_fdot2(qa, ka, pr, false);
        half2_t qb = {q1[2 * e], q1[2 * e + 1]};
        half2_t kb = {k1[2 * e], k1[2 * e + 1]};
        pr = __builtin_amdgcn_fdot2(qb, kb, pr, false);
      }
#else
#pragma unroll
      for (int e = 0; e < 8; ++e) {
        pr = fmaf((float)q0[e], (float)k0[e], pr);
        pr = fmaf((float)q1[e], (float)k1[e], pr);
      }
#endif
      pr += __shfl_xor(pr, 1, 64);      // combine the two 16-dim halves
      l[di * KW + dj] = pr * SCALE;
    }
  }

  float mx = l[0];
#pragma unroll
  for (int s = 1; s < 49; ++s) mx = fmaxf(mx, l[s]);
  float sum = 0.f;
#pragma unroll
  for (int s = 0; s < 49; ++s) {
    const float w = __expf(l[s] - mx);
    l[s] = w;
    sum += w;
  }
  const float inv = 1.f / sum;

  float o[16];
#pragma unroll
  for (int e = 0; e < 16; ++e) o[e] = 0.f;
#pragma unroll
  for (int di = 0; di < KW; ++di) {
#pragma unroll
    for (int dj = 0; dj < KW; ++dj) {
      const int hp = (pi + di) * HC + (pj + dj);
      const float w = l[di * KW + dj];
      const _Float16* vp = &vs16[hp * KST + dbase];
      const half8 v0 = *(const half8*)vp;
      const half8 v1 = *(const half8*)(vp + 8);
#pragma unroll
      for (int e = 0; e < 8; ++e) {
        o[e] = fmaf(w, (float)v0[e], o[e]);
        o[8 + e] = fmaf(w, (float)v1[e], o[8 + e]);
      }
    }
  }

  half8 r0, r1;
#pragma unroll
  for (int e = 0; e < 8; ++e) {
    r0[e] = (_Float16)(o[e] * inv);
    r1[e] = (_Float16)(o[8 + e] * inv);
  }
  _Float16* op = p.at16 + (size_t)n * 128 + h * 32 + dbase;
  *(half8*)op = r0;
  *(half8*)(op + 8) = r1;
}

// ---------------------------------------------------------------------------
// K3: projection GEMM (R8 verbatim): block-local Wproj->fp16, A from global.
// ---------------------------------------------------------------------------
__global__ __launch_bounds__(256) void gemm2_kernel(Params p) {
  __shared__ __align__(16) _Float16 wsh[64 * WSTRIDE];
  const int tid = threadIdx.x;
  const int m0 = blockIdx.x * 64;
  const int n0 = blockIdx.y * 64;

  stage_rows_f16(p.Wproj + (size_t)n0 * 128, wsh, tid);
  __syncthreads();

  const int lane = tid & 63;
  const int w = tid >> 6;
  const int r = lane & 15;
  const int quad = lane >> 4;
  const _Float16* ap = p.at16 + (size_t)(m0 + w * 16 + r) * 128 + quad * 8;
  const _Float16* bp = wsh + r * WSTRIDE + quad * 8;

  floatx4 acc0 = {0.f, 0.f, 0.f, 0.f};
  floatx4 acc1 = acc0, acc2 = acc0, acc3 = acc0;
#pragma unroll
  for (int kc = 0; kc < 4; ++kc) {
    const half8 a  = *(const half8*)(ap + kc * 32);
    const half8 b0 = *(const half8*)(bp + kc * 32);
    const half8 b1 = *(const half8*)(bp + 16 * WSTRIDE + kc * 32);
    const half8 b2 = *(const half8*)(bp + 32 * WSTRIDE + kc * 32);
    const half8 b3 = *(const half8*)(bp + 48 * WSTRIDE + kc * 32);
    acc0 = __builtin_amdgcn_mfma_f32_16x16x32_f16(a, b0, acc0, 0, 0, 0);
    acc1 = __builtin_amdgcn_mfma_f32_16x16x32_f16(a, b1, acc1, 0, 0, 0);
    acc2 = __builtin_amdgcn_mfma_f32_16x16x32_f16(a, b2, acc2, 0, 0, 0);
    acc3 = __builtin_amdgcn_mfma_f32_16x16x32_f16(a, b3, acc3, 0, 0, 0);
  }

  const int mbase = m0 + w * 16 + quad * 4;
  floatx4 accs[4] = {acc0, acc1, acc2, acc3};
#pragma unroll
  for (int nt = 0; nt < 4; ++nt) {
    const int n = n0 + nt * 16 + r;
    const float bv = p.bproj[n];
    float* cp = p.out + (size_t)mbase * 128 + n;
#pragma unroll
    for (int reg = 0; reg < 4; ++reg)
      cp[(size_t)reg * 128] = accs[nt][reg] + bv;
  }
}

// ---------------------------------------------------------------------------
// Workspace (18 MB):
//   [1 MB, 13 MB)   qkv16  [3][16384][128] fp16 planar
//   [14 MB, 18 MB)  at16   [16384][128] fp16
// ---------------------------------------------------------------------------
extern "C" void kernel_launch(void* const* d_in, const int* in_sizes, int n_in,
                              void* d_out, int out_size, void* d_ws, size_t ws_size,
                              hipStream_t stream) {
  char* ws = (char*)d_ws;
  Params hp;
  hp.x     = (const float*)d_in[0];
  hp.ctx   = (const float*)d_in[1];
  hp.Wqkv  = (const float*)d_in[2];
  hp.bqkv  = (const float*)d_in[3];
  hp.A     = (const float*)d_in[4];
  hp.Blora = (const float*)d_in[5];
  hp.Vlora = (const float*)d_in[6];
  hp.g1w   = (const float*)d_in[7];
  hp.g1b   = (const float*)d_in[8];
  hp.g2w   = (const float*)d_in[9];
  hp.g2b   = (const float*)d_in[10];
  hp.Wproj = (const float*)d_in[11];
  hp.bproj = (const float*)d_in[12];
  hp.out   = (float*)d_out;
  hp.qkv16 = (_Float16*)(ws + (1u << 20));
  hp.at16  = (_Float16*)(ws + (14u << 20));

  gemm1_kernel<<<dim3(64, 6, 4), 256, 0, stream>>>(hp);
  attn_kernel<<<512, 256, 0, stream>>>(hp);
  gemm2_kernel<<<dim3(256, 2), 256, 0, stream>>>(hp);
}

// Round 11
// 131.470 us; speedup vs baseline: 1.1667x; 1.0057x over previous
//
#include <hip/hip_runtime.h>
#include <cstddef>

#define CTXDIM 256
#define RANK 8
#define KW 7
#define SCALE 0.17677669529663687f
#define NPIX 16384
#define PLANE16 (NPIX * 128)   // elems per fp16 qkv plane
#define AH 14                  // attn halo rows = cols (8 + 6)
#define ANH 196                // 14*14
#define KST 40                 // fp16 LDS stride per halo pixel (80 B)
#define WSTRIDE 136            // fp16 LDS tile stride for GEMM staging

typedef _Float16 half8 __attribute__((ext_vector_type(8)));
typedef _Float16 half2_t __attribute__((ext_vector_type(2)));
typedef float floatx4 __attribute__((ext_vector_type(4)));

#if defined(__has_builtin)
#if __has_builtin(__builtin_amdgcn_fdot2)
#define HAVE_FDOT2 1
#endif
#endif

struct Params {
  const float *x, *ctx, *Wqkv, *bqkv, *A, *Blora, *Vlora;
  const float *g1w, *g1b, *g2w, *g2b, *Wproj, *bproj;
  float* out;
  _Float16* qkv16;   // planar fp16 [3][N][128]
  _Float16* at16;    // attention output fp16 [N][128]
};

// ---- cal[b][r] = alpha_b * (ctx[b] @ Blora)[r]; wave b handles batch b ----
__device__ __forceinline__ void compute_cal(const Params& p, int tid,
                                            float* cal_s) {
  const int b = tid >> 6, lane = tid & 63;
  const float c0 = p.ctx[b * CTXDIM + lane];
  const float c1 = p.ctx[b * CTXDIM + 64 + lane];
  const float c2 = p.ctx[b * CTXDIM + 128 + lane];
  const float c3 = p.ctx[b * CTXDIM + 192 + lane];
  float cp[RANK];
#pragma unroll
  for (int r = 0; r < RANK; ++r) {
    float q = c0 * p.Blora[lane * RANK + r] + c1 * p.Blora[(64 + lane) * RANK + r] +
              c2 * p.Blora[(128 + lane) * RANK + r] + c3 * p.Blora[(192 + lane) * RANK + r];
#pragma unroll
    for (int s = 32; s; s >>= 1) q += __shfl_xor(q, s, 64);
    cp[r] = q;
  }
  float gacc = 0.f;
#pragma unroll
  for (int h = 0; h < 16; ++h) {
    float q = c0 * p.g1w[h * CTXDIM + lane] + c1 * p.g1w[h * CTXDIM + 64 + lane] +
              c2 * p.g1w[h * CTXDIM + 128 + lane] + c3 * p.g1w[h * CTXDIM + 192 + lane];
#pragma unroll
    for (int s = 32; s; s >>= 1) q += __shfl_xor(q, s, 64);
    gacc += fmaxf(q + p.g1b[h], 0.f) * p.g2w[h];
  }
  if (lane == 0) {
    const float alpha = 1.f / (1.f + __expf(-(gacc + p.g2b[0])));
#pragma unroll
    for (int r = 0; r < RANK; ++r) cal_s[b * RANK + r] = alpha * cp[r];
  }
}

// ---- stage 64 fp32 rows (row stride 128) -> LDS fp16 [64][WSTRIDE] ----
__device__ __forceinline__ void stage_rows_f16(const float* __restrict__ src,
                                               _Float16* dst, int tid) {
  const int row = tid >> 2;
  const int c0 = (tid & 3) * 32;
  const float* sp = src + (size_t)row * 128 + c0;
  _Float16* dp = dst + row * WSTRIDE + c0;
#pragma unroll
  for (int i = 0; i < 4; ++i) {
    const float4 a = *(const float4*)(sp + i * 8);
    const float4 b = *(const float4*)(sp + i * 8 + 4);
    half8 o;
    o[0] = (_Float16)a.x; o[1] = (_Float16)a.y;
    o[2] = (_Float16)a.z; o[3] = (_Float16)a.w;
    o[4] = (_Float16)b.x; o[5] = (_Float16)b.y;
    o[6] = (_Float16)b.z; o[7] = (_Float16)b.w;
    *(half8*)(dp + i * 8) = o;
  }
}

// ---------------------------------------------------------------------------
// K1: QKV GEMM, block-local prep.  Grid (64, 2, 4): block (bx, byg, z) stages
// its 64-row x-tile ONCE, then loops 3 n-tiles (byg*3+i)*64: fold Weff rows
// into LDS fp16 -> MFMA -> planar fp16 write.  x L2 reads drop 6x -> 2x;
// identical fp16 rounding path => qkv16 bit-identical to R10.
// ---------------------------------------------------------------------------
__global__ __launch_bounds__(256) void gemm1_kernel(Params p) {
  __shared__ __align__(16) _Float16 xs[64 * WSTRIDE];
  __shared__ __align__(16) _Float16 wsh[64 * WSTRIDE];
  __shared__ float cal_s[32];
  const int tid = threadIdx.x;
  const int bx = blockIdx.x, byg = blockIdx.y, z = blockIdx.z;
  const int m0 = z * 4096 + bx * 64;

  compute_cal(p, tid, cal_s);
  stage_rows_f16(p.x + (size_t)m0 * 128, xs, tid);
  __syncthreads();

  const int lane = tid & 63;
  const int w = tid >> 6;
  const int r = lane & 15;
  const int quad = lane >> 4;
  const int k = tid & 127;
  const int hgrp = tid >> 7;
  const float4 a0 = *(const float4*)&p.A[k * RANK];
  const float4 a1 = *(const float4*)&p.A[k * RANK + 4];
  const float* cb = &cal_s[z * RANK];
  const float c0 = cb[0], c1 = cb[1], c2 = cb[2], c3 = cb[3];
  const float c4 = cb[4], c5 = cb[5], c6 = cb[6], c7 = cb[7];

  for (int i = 0; i < 3; ++i) {
    const int n0 = (byg * 3 + i) * 64;

    // fold Weff rows n0..n0+63 into wsh (fp16)
#pragma unroll
    for (int rr = 0; rr < 32; ++rr) {
      const int row = hgrp * 32 + rr;
      const int o = n0 + row;
      const float4 v0 = *(const float4*)&p.Vlora[o * RANK];
      const float4 v1 = *(const float4*)&p.Vlora[o * RANK + 4];
      float d = a0.x * v0.x * c0;
      d = fmaf(a0.y * v0.y, c1, d);
      d = fmaf(a0.z * v0.z, c2, d);
      d = fmaf(a0.w * v0.w, c3, d);
      d = fmaf(a1.x * v1.x, c4, d);
      d = fmaf(a1.y * v1.y, c5, d);
      d = fmaf(a1.z * v1.z, c6, d);
      d = fmaf(a1.w * v1.w, c7, d);
      wsh[row * WSTRIDE + k] = (_Float16)(p.Wqkv[o * 128 + k] + d);
    }
    __syncthreads();

    const _Float16* ap = xs + (w * 16 + r) * WSTRIDE + quad * 8;
    const _Float16* bp = wsh + r * WSTRIDE + quad * 8;
    floatx4 acc0 = {0.f, 0.f, 0.f, 0.f};
    floatx4 acc1 = acc0, acc2 = acc0, acc3 = acc0;
#pragma unroll
    for (int kc = 0; kc < 4; ++kc) {
      const half8 a  = *(const half8*)(ap + kc * 32);
      const half8 b0 = *(const half8*)(bp + kc * 32);
      const half8 b1 = *(const half8*)(bp + 16 * WSTRIDE + kc * 32);
      const half8 b2 = *(const half8*)(bp + 32 * WSTRIDE + kc * 32);
      const half8 b3 = *(const half8*)(bp + 48 * WSTRIDE + kc * 32);
      acc0 = __builtin_amdgcn_mfma_f32_16x16x32_f16(a, b0, acc0, 0, 0, 0);
      acc1 = __builtin_amdgcn_mfma_f32_16x16x32_f16(a, b1, acc1, 0, 0, 0);
      acc2 = __builtin_amdgcn_mfma_f32_16x16x32_f16(a, b2, acc2, 0, 0, 0);
      acc3 = __builtin_amdgcn_mfma_f32_16x16x32_f16(a, b3, acc3, 0, 0, 0);
    }

    const int mbase = m0 + w * 16 + quad * 4;
    floatx4 accs[4] = {acc0, acc1, acc2, acc3};
#pragma unroll
    for (int nt = 0; nt < 4; ++nt) {
      const int ncol = n0 + nt * 16 + r;
      const float bv = p.bqkv[ncol];
      _Float16* cp = p.qkv16 + (size_t)(ncol >> 7) * PLANE16 +
                     (size_t)mbase * 128 + (ncol & 127);
#pragma unroll
      for (int reg = 0; reg < 4; ++reg)
        cp[(size_t)reg * 128] = (_Float16)(accs[nt][reg] + bv);
    }
    if (i != 2) __syncthreads();   // protect wsh before next fold
  }
}

// ---------------------------------------------------------------------------
// K2: neighborhood attention, fp16 K/V LDS path, 4 blocks/CU.
// Block = (b, ti, tj, h): 8x8 pixel tile, one head; 1024 blocks.
// 4 threads/pixel (8 dims each).  14x14 fp16 K AND V halos staged at once
// (31.4 KB LDS, one barrier).  Zero-fill OOB = reference zero-pad softmax.
// Logits: fdot2 + 2 xor-shuffles; online max.  PV fp32 accumulate.
// ---------------------------------------------------------------------------
__global__ __launch_bounds__(256) void attn_kernel(Params p) {
  __shared__ __align__(16) _Float16 ks16[ANH * KST];
  __shared__ __align__(16) _Float16 vs16[ANH * KST];

  const int bid = blockIdx.x;        // [0,1024)
  const int h  = bid & 3;
  const int tj = (bid >> 2) & 7;
  const int ti = (bid >> 5) & 7;
  const int b  = bid >> 8;
  const int tid = threadIdx.x;

  const _Float16* kpl = p.qkv16 + PLANE16;
  const _Float16* vpl = p.qkv16 + 2 * (size_t)PLANE16;

  // ---- per-thread mapping + hoisted q load (overlaps staging) ----
  const int pix = tid >> 2;          // 0..63
  const int qtr = tid & 3;           // dim quarter (8 dims)
  const int pi = pix >> 3;
  const int pj = pix & 7;
  const int n = b * 4096 + (ti * 8 + pi) * 64 + tj * 8 + pj;
  const int dbase = qtr * 8;
  const half8 q0 = *(const half8*)(p.qkv16 + (size_t)n * 128 + h * 32 + dbase);

  // ---- stage K and V halos (196 pixels x 32 fp16 dims each) ----
  const int i0 = ti * 8 - 3;
  const int j0 = tj * 8 - 3;
#pragma unroll
  for (int it = 0; it < 4; ++it) {
    const int s = tid + it * 256;     // half8 slot, [0,784)
    if (s < ANH * 4) {
      const int pp = s >> 2;
      const int d8 = (s & 3) * 8;
      const int hr = pp / AH;
      const int hc = pp - hr * AH;
      const int ii = i0 + hr;
      const int jj = j0 + hc;
      half8 kv = {0, 0, 0, 0, 0, 0, 0, 0};
      half8 vv = {0, 0, 0, 0, 0, 0, 0, 0};
      if ((unsigned)ii < 64u && (unsigned)jj < 64u) {
        const size_t g = (size_t)(b * 4096 + ii * 64 + jj) * 128 + h * 32 + d8;
        kv = *(const half8*)(kpl + g);
        vv = *(const half8*)(vpl + g);
      }
      *(half8*)&ks16[pp * KST + d8] = kv;
      *(half8*)&vs16[pp * KST + d8] = vv;
    }
  }
  __syncthreads();

  // ---- logits (online max) ----
  float l[49];
  float mx = -1e30f;
#pragma unroll
  for (int di = 0; di < KW; ++di) {
#pragma unroll
    for (int dj = 0; dj < KW; ++dj) {
      const int hp = (pi + di) * AH + (pj + dj);
      const half8 k0 = *(const half8*)&ks16[hp * KST + dbase];
      float pr = 0.f;
#ifdef HAVE_FDOT2
#pragma unroll
      for (int e = 0; e < 4; ++e) {
        half2_t qa = {q0[2 * e], q0[2 * e + 1]};
        half2_t ka = {k0[2 * e], k0[2 * e + 1]};
        pr = __builtin_amdgcn_fdot2(qa, ka, pr, false);
      }
#else
#pragma unroll
      for (int e = 0; e < 8; ++e)
        pr = fmaf((float)q0[e], (float)k0[e], pr);
#endif
      pr += __shfl_xor(pr, 1, 64);    // combine 4 dim-quarters
      pr += __shfl_xor(pr, 2, 64);
      const float lv = pr * SCALE;
      l[di * KW + dj] = lv;
      mx = fmaxf(mx, lv);
    }
  }

  float sum = 0.f;
#pragma unroll
  for (int s = 0; s < 49; ++s) {
    const float w = __expf(l[s] - mx);
    l[s] = w;
    sum += w;
  }
  const float inv = 1.f / sum;

  // ---- PV ----
  float o[8];
#pragma unroll
  for (int e = 0; e < 8; ++e) o[e] = 0.f;
#pragma unroll
  for (int di = 0; di < KW; ++di) {
#pragma unroll
    for (int dj = 0; dj < KW; ++dj) {
      const int hp = (pi + di) * AH + (pj + dj);
      const float w = l[di * KW + dj];
      const half8 v0 = *(const half8*)&vs16[hp * KST + dbase];
#pragma unroll
      for (int e = 0; e < 8; ++e)
        o[e] = fmaf(w, (float)v0[e], o[e]);
    }
  }

  half8 r0;
#pragma unroll
  for (int e = 0; e < 8; ++e) r0[e] = (_Float16)(o[e] * inv);
  *(half8*)(p.at16 + (size_t)n * 128 + h * 32 + dbase) = r0;
}

// ---------------------------------------------------------------------------
// K3: projection GEMM (unchanged): block-local Wproj->fp16, A from global.
// ---------------------------------------------------------------------------
__global__ __launch_bounds__(256) void gemm2_kernel(Params p) {
  __shared__ __align__(16) _Float16 wsh[64 * WSTRIDE];
  const int tid = threadIdx.x;
  const int m0 = blockIdx.x * 64;
  const int n0 = blockIdx.y * 64;

  stage_rows_f16(p.Wproj + (size_t)n0 * 128, wsh, tid);
  __syncthreads();

  const int lane = tid & 63;
  const int w = tid >> 6;
  const int r = lane & 15;
  const int quad = lane >> 4;
  const _Float16* ap = p.at16 + (size_t)(m0 + w * 16 + r) * 128 + quad * 8;
  const _Float16* bp = wsh + r * WSTRIDE + quad * 8;

  floatx4 acc0 = {0.f, 0.f, 0.f, 0.f};
  floatx4 acc1 = acc0, acc2 = acc0, acc3 = acc0;
#pragma unroll
  for (int kc = 0; kc < 4; ++kc) {
    const half8 a  = *(const half8*)(ap + kc * 32);
    const half8 b0 = *(const half8*)(bp + kc * 32);
    const half8 b1 = *(const half8*)(bp + 16 * WSTRIDE + kc * 32);
    const half8 b2 = *(const half8*)(bp + 32 * WSTRIDE + kc * 32);
    const half8 b3 = *(const half8*)(bp + 48 * WSTRIDE + kc * 32);
    acc0 = __builtin_amdgcn_mfma_f32_16x16x32_f16(a, b0, acc0, 0, 0, 0);
    acc1 = __builtin_amdgcn_mfma_f32_16x16x32_f16(a, b1, acc1, 0, 0, 0);
    acc2 = __builtin_amdgcn_mfma_f32_16x16x32_f16(a, b2, acc2, 0, 0, 0);
    acc3 = __builtin_amdgcn_mfma_f32_16x16x32_f16(a, b3, acc3, 0, 0, 0);
  }

  const int mbase = m0 + w * 16 + quad * 4;
  floatx4 accs[4] = {acc0, acc1, acc2, acc3};
#pragma unroll
  for (int nt = 0; nt < 4; ++nt) {
    const int n = n0 + nt * 16 + r;
    const float bv = p.bproj[n];
    float* cp = p.out + (size_t)mbase * 128 + n;
#pragma unroll
    for (int reg = 0; reg < 4; ++reg)
      cp[(size_t)reg * 128] = accs[nt][reg] + bv;
  }
}

// ---------------------------------------------------------------------------
// Workspace (18 MB):
//   [1 MB, 13 MB)   qkv16  [3][16384][128] fp16 planar
//   [14 MB, 18 MB)  at16   [16384][128] fp16
// ---------------------------------------------------------------------------
extern "C" void kernel_launch(void* const* d_in, const int* in_sizes, int n_in,
                              void* d_out, int out_size, void* d_ws, size_t ws_size,
                              hipStream_t stream) {
  char* ws = (char*)d_ws;
  Params hp;
  hp.x     = (const float*)d_in[0];
  hp.ctx   = (const float*)d_in[1];
  hp.Wqkv  = (const float*)d_in[2];
  hp.bqkv  = (const float*)d_in[3];
  hp.A     = (const float*)d_in[4];
  hp.Blora = (const float*)d_in[5];
  hp.Vlora = (const float*)d_in[6];
  hp.g1w   = (const float*)d_in[7];
  hp.g1b   = (const float*)d_in[8];
  hp.g2w   = (const float*)d_in[9];
  hp.g2b   = (const float*)d_in[10];
  hp.Wproj = (const float*)d_in[11];
  hp.bproj = (const float*)d_in[12];
  hp.out   = (float*)d_out;
  hp.qkv16 = (_Float16*)(ws + (1u << 20));
  hp.at16  = (_Float16*)(ws + (14u << 20));

  gemm1_kernel<<<dim3(64, 2, 4), 256, 0, stream>>>(hp);
  attn_kernel<<<1024, 256, 0, stream>>>(hp);
  gemm2_kernel<<<dim3(256, 2), 256, 0, stream>>>(hp);
}